// Round 1
// 128.765 us; speedup vs baseline: 1.0071x; 1.0071x over previous
//
#include <hip/hip_runtime.h>

#define NUM_NODES   120000
#define NUM_MOVABLE 100000
#define NUM_NETS    100000
#define NUM_PINS    400000
#define NBX 256
#define NBY 256
#define GRID_BINS (NBX*NBY)
#define NSB 391             // scatter blocks = ceil(NUM_NETS/256); also #segments/row
#define SEGCAP 32           // per-(row,block) segment capacity (max expected ~18)

constexpr float BSX      = 1000.0f / 256.0f;   // 3.90625 exact in binary
constexpr float INV_BS   = 256.0f / 1000.0f;
constexpr float BIN_AREA = BSX * BSX;
constexpr float EPSV     = 1e-6f;

// Workspace layout (elements):
//   bbox:   float4[NUM_NETS]   NOT initialized; only written for non-empty
//           nets, and only read via scattered entries (which reference
//           exactly the nets that wrote it). Empty nets never scattered.
//   cnt_rb: u32[256*NSB]       per-(row,segment) entry counts (plain stores)
//   entries:u32[256*NSB*SEGCAP] (net<<1)|side, private per (row,segment)
//   A_hT,B_hT,A_vT,B_vT: float[GRID_BINS] transposed [y*NBX+x]
//   util:   float[GRID_BINS]   [x*NBY+y]
// H(x,y) = A_h(x,y) + sum_{x'<x} B_h(x',y); same for V.

// Wave-level inclusive scans (64-lane): replaces LDS Hillis-Steele scans
// that cost 2 barriers per step x 8-9 steps on 16-wave blocks.
__device__ __forceinline__ float wave_iscan_f(float v, int lane) {
    #pragma unroll
    for (int d = 1; d < 64; d <<= 1) {
        float u = __shfl_up(v, d, 64);
        if (lane >= d) v += u;
    }
    return v;
}
__device__ __forceinline__ unsigned wave_iscan_u(unsigned v, int lane) {
    #pragma unroll
    for (int d = 1; d < 64; d <<= 1) {
        unsigned u = __shfl_up(v, d, 64);
        if (lane >= d) v += u;
    }
    return v;
}

// ------------------------------------------------------- bbox + scatter
// One thread per net: serial pin loop (iterations independent -> pipelined
// gathers), sole-owner bbox store (NO atomics, NO init needed), then
// private-segment scatter via LDS cursors (NO global atomics).
__global__ void bbox_scatter(const float* __restrict__ pin_pos,
                             const int* __restrict__ netpin_start,
                             const int* __restrict__ flat_netpin,
                             float4* __restrict__ bbox,
                             unsigned* __restrict__ cnt_rb,
                             unsigned* __restrict__ entries) {
    __shared__ unsigned cur[256];
    int tid = threadIdx.x, blk = blockIdx.x;
    if (tid < 256) cur[tid] = 0u;
    __syncthreads();
    int n = blk * 256 + tid;
    if (n < NUM_NETS) {
        int s = netpin_start[n], e = netpin_start[n + 1];
        if (e > s) {
            float xmn = 3.4e38f, xmx = -3.4e38f, ymn = 3.4e38f, ymx = -3.4e38f;
            for (int i = s; i < e; ++i) {
                int p = flat_netpin[i];
                float px = pin_pos[p];
                float py = pin_pos[NUM_PINS + p];
                xmn = fminf(xmn, px); xmx = fmaxf(xmx, px);
                ymn = fminf(ymn, py); ymx = fmaxf(ymx, py);
            }
            bbox[n] = make_float4(xmn, ymn, xmx, ymx);
            if ((ymx - ymn) > EPSV || (xmx - xmn) > EPSV) {
                unsigned bxl = (unsigned)min((int)(xmn * INV_BS), NBX - 1);
                unsigned bxh = (unsigned)min((int)(xmx * INV_BS), NBX - 1);
                unsigned p0 = atomicAdd(&cur[bxl], 1u);
                if (p0 < SEGCAP)
                    entries[(bxl * NSB + blk) * SEGCAP + p0] = (unsigned)(n << 1);
                unsigned p1 = atomicAdd(&cur[bxh], 1u);
                if (p1 < SEGCAP)
                    entries[(bxh * NSB + blk) * SEGCAP + p1] = (unsigned)(n << 1) | 1u;
            }
        }
    }
    __syncthreads();
    if (tid < 256) cnt_rb[tid * NSB + blk] = min(cur[tid], (unsigned)SEGCAP);
}

// ---------------------------------------------------------------- splat phase
// One block per bx row. Segment-count prefix via wave shfl scan + 8-way
// cross-wave fixup (2 barriers, was 18). Entry walk with LDS accumulation.
// y-scan of the 4 carry fields via wave shfl scans, 4 chunks of 64 per
// field, 16 waves cover all 4 fields in one shot (1 barrier, was 16).
// F is never rewritten in place. Total 5 barriers (was ~36).
__global__ __launch_bounds__(1024) void splat_rows(
        const float4* __restrict__ bbox,
        const unsigned* __restrict__ cnt_rb,
        const unsigned* __restrict__ entries,
        float* __restrict__ A_hT, float* __restrict__ B_hT,
        float* __restrict__ A_vT, float* __restrict__ B_vT) {
    int bx = blockIdx.x;
    int t  = threadIdx.x;
    int lane = t & 63;
    __shared__ float    F[8][NBY];  // 0 P_h, 1 CX_h, 2 CY_h, 3 Q_h, 4..7 same V
    __shared__ unsigned S[512];     // inclusive segment-count prefix
    __shared__ unsigned Wsum[8];    // per-wave partial sums of the S-scan
    __shared__ float    Ysum[4][4]; // per-field per-64-chunk partials of y-scan
    for (int i = t; i < 8 * NBY; i += 1024) ((float*)F)[i] = 0.0f;
    unsigned sc = 0u;
    if (t < 512) {
        unsigned v = (t < NSB) ? cnt_rb[bx * NSB + t] : 0u;
        sc = wave_iscan_u(v, lane);
        if (lane == 63) Wsum[t >> 6] = sc;
    }
    __syncthreads();                 // covers F init + Wsum
    if (t < 512) {
        unsigned off = 0u;
        int ch = t >> 6;
        for (int c = 0; c < ch; ++c) off += Wsum[c];
        S[t] = sc + off;
    }
    __syncthreads();
    int total = (int)S[NSB - 1];

    for (int j = t; j < total; j += 1024) {
        // segment = upper_bound over inclusive prefix S
        int lo = 0, hi = NSB;
        while (lo < hi) {
            int mid = (lo + hi) >> 1;
            if ((int)S[mid] <= j) lo = mid + 1; else hi = mid;
        }
        int off = j - (lo > 0 ? (int)S[lo - 1] : 0);
        unsigned e = entries[(bx * NSB + lo) * SEGCAP + off];
        int n = (int)(e >> 1), side = (int)(e & 1u);
        float4 b = bbox[n];
        float span_x = b.z - b.x, span_y = b.w - b.y;
        float coef_h = (span_y > EPSV) ? 1.0f / span_y : 0.0f;
        float coef_v = (span_x > EPSV) ? 1.0f / span_x : 0.0f;
        int byl = min((int)(b.y * INV_BS), NBY - 1);
        int byh = min((int)(b.w * INV_BS), NBY - 1);
        float ryl = (float)(byl + 1) * BSX - b.y;
        float ryh = (float)(byh + 1) * BSX - b.w;
        float rx, s0;
        if (side == 0) {
            int bxl = min((int)(b.x * INV_BS), NBX - 1);
            rx = (float)(bxl + 1) * BSX - b.x; s0 = 1.0f;
        } else {
            int bxh = min((int)(b.z * INV_BS), NBX - 1);
            rx = (float)(bxh + 1) * BSX - b.z; s0 = -1.0f;
        }
        if (coef_h != 0.0f) {
            float w0 = s0 * coef_h, w1 = -s0 * coef_h;
            atomicAdd(&F[0][byl], w0 * rx  * ryl);
            atomicAdd(&F[1][byl], w0 * rx  * BSX);
            atomicAdd(&F[2][byl], w0 * BSX * ryl);
            atomicAdd(&F[3][byl], w0 * BSX * BSX);
            atomicAdd(&F[0][byh], w1 * rx  * ryh);
            atomicAdd(&F[1][byh], w1 * rx  * BSX);
            atomicAdd(&F[2][byh], w1 * BSX * ryh);
            atomicAdd(&F[3][byh], w1 * BSX * BSX);
        }
        if (coef_v != 0.0f) {
            float w0 = s0 * coef_v, w1 = -s0 * coef_v;
            atomicAdd(&F[4][byl], w0 * rx  * ryl);
            atomicAdd(&F[5][byl], w0 * rx  * BSX);
            atomicAdd(&F[6][byl], w0 * BSX * ryl);
            atomicAdd(&F[7][byl], w0 * BSX * BSX);
            atomicAdd(&F[4][byh], w1 * rx  * ryh);
            atomicAdd(&F[5][byh], w1 * rx  * BSX);
            atomicAdd(&F[6][byh], w1 * BSX * ryh);
            atomicAdd(&F[7][byh], w1 * BSX * BSX);
        }
    }
    __syncthreads();

    // Inclusive y-scan of fields 1,3,5,7 (CX_h, Q_h, CX_v, Q_v) via shfl.
    // Field g handled by waves 4g..4g+3; chunk = 64-wide slice within field.
    int g = t >> 8, y = t & 255, chunk = (t >> 6) & 3;
    float val = F[2 * g + 1][y];
    float isc = wave_iscan_f(val, lane);
    if (lane == 63) Ysum[g][chunk] = isc;
    __syncthreads();
    float yoff = 0.0f;
    for (int c = 0; c < chunk; ++c) yoff += Ysum[g][c];
    // exclusive(CX)[y] = inclusive[y] - own; A = P + exclusive(CX), etc.
    float ex   = isc + yoff - val;
    float outv = F[2 * g][y] + ex;
    float* o   = (g == 0) ? A_hT : (g == 1) ? B_hT : (g == 2) ? A_vT : B_vT;
    o[y * NBX + bx] = outv;
}

// ---------------------------------------------------------------- x-scan+util
// One block per y (256 threads = 4 waves). Shfl scan of (B_h,B_v) pairs +
// 4-way cross-wave fixup: 1 barrier (was 16). Coalesced transposed reads.
__global__ void scan_x_util(const float* __restrict__ A_hT, const float* __restrict__ B_hT,
                            const float* __restrict__ A_vT, const float* __restrict__ B_vT,
                            float* __restrict__ util) {
    int y = blockIdx.x, x = threadIdx.x;
    int lane = x & 63, wid = x >> 6;
    int idxT = y * NBX + x;
    __shared__ float Wh[4], Wv[4];
    float bh = B_hT[idxT], bv = B_vT[idxT];
    float sh = bh, sv = bv;
    #pragma unroll
    for (int d = 1; d < 64; d <<= 1) {
        float uh = __shfl_up(sh, d, 64);
        float uv = __shfl_up(sv, d, 64);
        if (lane >= d) { sh += uh; sv += uv; }
    }
    if (lane == 63) { Wh[wid] = sh; Wv[wid] = sv; }
    __syncthreads();
    float oh = 0.f, ov = 0.f;
    for (int c = 0; c < wid; ++c) { oh += Wh[c]; ov += Wv[c]; }
    float H = A_hT[idxT] + (sh + oh - bh);   // A + exclusive(B)
    float V = A_vT[idxT] + (sv + ov - bv);
    float u = fmaxf(H, V) * (1.0f / (BIN_AREA * 1.5f));
    util[x * NBY + y] = fminf(fmaxf(u, 0.5f), 2.0f);
}

// ---------------------------------------------------------------- node phase
__global__ void node_area(const float* __restrict__ pos,
                          const float* __restrict__ nsx,
                          const float* __restrict__ nsy,
                          const float* __restrict__ util,
                          float* __restrict__ out) {
    int m = blockIdx.x * 256 + threadIdx.x;
    if (m >= NUM_MOVABLE) return;
    float xl = pos[m];
    float yl = pos[NUM_NODES + m];
    float xh = xl + nsx[m];
    float yh = yl + nsy[m];
    int bx0 = max(0, min((int)(xl * INV_BS), NBX - 1));
    int bx1 = max(0, min((int)(xh * INV_BS), NBX - 1));
    int by0 = max(0, min((int)(yl * INV_BS), NBY - 1));
    int by1 = max(0, min((int)(yh * INV_BS), NBY - 1));
    float acc = 0.0f;
    for (int bx = bx0; bx <= bx1; ++bx) {
        float ox = fminf(xh, (float)(bx + 1) * BSX) - fmaxf(xl, (float)bx * BSX);
        if (ox <= 0.0f) continue;
        const float* urow = util + bx * NBY;
        float inner = 0.0f;
        for (int by = by0; by <= by1; ++by) {
            float oy = fminf(yh, (float)(by + 1) * BSX) - fmaxf(yl, (float)by * BSX);
            if (oy > 0.0f) inner += oy * urow[by];
        }
        acc += ox * inner;
    }
    out[m] = acc;
}

extern "C" void kernel_launch(void* const* d_in, const int* in_sizes, int n_in,
                              void* d_out, int out_size, void* d_ws, size_t ws_size,
                              hipStream_t stream) {
    const float* pos          = (const float*)d_in[0];
    const float* pin_pos      = (const float*)d_in[1];
    const float* node_size_x  = (const float*)d_in[2];
    const float* node_size_y  = (const float*)d_in[3];
    const int*   netpin_start = (const int*)d_in[4];
    const int*   flat_netpin  = (const int*)d_in[5];

    float4*   bbox    = (float4*)d_ws;                          // 1.6 MB (no init)
    unsigned* cnt_rb  = (unsigned*)(bbox + NUM_NETS);           // 400 KB
    unsigned* entries = cnt_rb + 256 * NSB;                     // 12.8 MB
    float*    A_hT    = (float*)(entries + 256 * NSB * SEGCAP); // 4 x 256 KB
    float*    B_hT    = A_hT + GRID_BINS;
    float*    A_vT    = B_hT + GRID_BINS;
    float*    B_vT    = A_vT + GRID_BINS;
    float*    util    = B_vT + GRID_BINS;                       // 256 KB
    float*    out     = (float*)d_out;

    bbox_scatter<<<NSB, 256, 0, stream>>>(
        pin_pos, netpin_start, flat_netpin, bbox, cnt_rb, entries);
    splat_rows<<<NBX, 1024, 0, stream>>>(bbox, cnt_rb, entries,
                                         A_hT, B_hT, A_vT, B_vT);
    scan_x_util<<<NBY, NBX, 0, stream>>>(A_hT, B_hT, A_vT, B_vT, util);
    node_area<<<(NUM_MOVABLE + 255) / 256, 256, 0, stream>>>(
        pos, node_size_x, node_size_y, util, out);
}